// Round 2
// baseline (214.810 us; speedup 1.0000x reference)
//
#include <hip/hip_runtime.h>

// NCC loss, fused single pass. Layout [n][1][d][h][w], n=2, d=160, h=192, w=192, f32.
// R7: kill the per-step DMA drain. R6 proved the kernel is latency-bound at the
//   end-of-step __syncthreads: it compiles to s_waitcnt vmcnt(0) lgkmcnt(0) +
//   s_barrier, and the double buffer's prefetch distance is ONE step (DMA issued at
//   top of step t must land by the bottom of step t). Removing 33% of the LDS work
//   in R6 changed nothing (84.5 us, VALUBusy 55->50) => the stall, not work, rules.
//   Fix (guide T3/T4): 3-buffer ring, prefetch distance 2, counted waits:
//     step t: read buf[t%3] (slice d_lo-2+t); issue DMA slice d_lo+t -> buf[(t+2)%3]
//     end of step: s_waitcnt vmcnt(3) lgkmcnt(0)  (drains the 3 OLDEST = step t-1's
//     DMAs, leaves this step's 3 in flight; m135: vmcnt retires oldest-first), then
//     raw s_barrier. DMA latency is now covered by two full steps of compute.
//   COUNT EXACTNESS: waves that issue nothing this step (t>=T-2, or slice>=Dd at the
//   last d-chunk; condition is wave-uniform) wait vmcnt(0) instead, so "leave newest
//   3" always means "leave exactly this step's 3". lgkmcnt(0) pre-barrier closes the
//   cross-wave race: another wave's DMA may overwrite a buffer this wave still has
//   an in-flight ds_read against (s_barrier alone does not drain lgkmcnt).
// R6 (kept): aligned layout col c <-> w = wbase-2+c; 2x aligned ds_read_b128 per
//   row/array; clamp-shift at the two W edges fixed by in-register permute (fixl/fixr).
// R5 (kept): all lanes always issue DMA with CLAMPED global addrs (m104/m108: LDS
//   dest is lane-linear from readfirstlane base; per-lane masking forbidden except
//   the r=2 tail lane<52 which keeps lane 0 active). H-OOB rows skipped in compute,
//   D-OOB slices skipped wave-uniformly, ring in registers, no occupancy clamp.

namespace {
constexpr int Wd = 192, Hd = 192, Dd = 160;
constexpr int SH = 192;              // h stride (floats)
constexpr int SD = 192 * 192;        // d stride
constexpr long SN = (long)SD * Dd;   // n stride
constexpr int CD = 6;                // d outputs per chunk; T = CD+4 = 10
constexpr int NCHUNK = 27;           // ceil(160/6)
constexpr int TROW = 72;             // LDS row stride (floats), unpadded (DMA lane map)
constexpr int TILEF = 2 * 20 * TROW; // floats per buffer (2880)
constexpr float INV_V = 1.0f / 125.0f;
constexpr float EPSf = 1e-5f;

__device__ __forceinline__ void wslide(const float h[8], float o[4]) {
  float s0 = h[0] + h[1] + h[2] + h[3] + h[4];
  float s1 = s0 - h[0] + h[5];
  float s2 = s1 - h[1] + h[6];
  float s3 = s2 - h[2] + h[7];
  o[0] = s0; o[1] = s1; o[2] = s2; o[3] = s3;
}

__device__ __forceinline__ void gl_lds16(const float* g, float* l) {
  __builtin_amdgcn_global_load_lds(
      (const __attribute__((address_space(1))) void*)g,
      (__attribute__((address_space(3))) void*)l, 16, 0, 0);
}
} // namespace

__global__ __launch_bounds__(256) void ncc_fused(const float* __restrict__ I,
                                                 const float* __restrict__ Jv,
                                                 float* __restrict__ out) {
  __shared__ float tile[3][TILEF];   // 34.56 KB triple buffer (prefetch distance 2)
  __shared__ float red[4];

  const int tid = threadIdx.x;
  const int tx = tid & 15;        // w-run index (4 outputs each)
  const int ty = tid >> 4;        // h row within 16-tall tile
  const int wbase = blockIdx.x * 64;
  const int hbase = blockIdx.y * 16;
  const int n  = blockIdx.z / NCHUNK;
  const int d_lo = (blockIdx.z % NCHUNK) * CD;

  const float* Ib = I  + (long)n * SN;
  const float* Jb = Jv + (long)n * SN;

  // ---- staging descriptors: 720 16B-segs; wave w owns segs [w*180,(w+1)*180) ----
  // seg = arr*360 + row*18 + c16 ; LDS byte-offset = seg*16 (consecutive per lane)
  // layout: LDS col c  <->  global w = wbase - 2 + c
  const int wave = tid >> 6, lane = tid & 63;
  const int arr = wave >> 1;                       // waves 0,1 -> I ; 2,3 -> J
  const float* gsrc = arr ? Jb : Ib;
  int goff[3]; int loff[3]; bool on[3];
  #pragma unroll
  for (int r = 0; r < 3; ++r) {
    const int seg = wave * 180 + r * 64 + lane;
    on[r] = (r < 2) || (lane < 52);                // 180 = 2*64 + 52 (lane 0 stays active)
    const int rem = seg - arr * 360;
    const int row = rem / 18, c16 = rem % 18;
    const int hh = hbase + row - 2;
    const int hc = min(max(hh, 0), Hd - 1);        // CLAMP, never mask
    const int gw = wbase - 2 + c16 * 4;
    const int gc = min(max(gw, 0), Wd - 4);
    goff[r] = hc * SH + gc;
    loff[r] = seg * 4;                             // float offset
  }

  // ---- prologue: stage slices d_lo-2 -> buf0, d_lo-1 -> buf1 ----
  // Both are in-range iff d_lo > 0 (d_lo is a multiple of 6), else both skipped.
  if (d_lo > 0) {
    const float* b0 = gsrc + (long)(d_lo - 2) * SD;
    const float* b1 = gsrc + (long)(d_lo - 1) * SD;
    #pragma unroll
    for (int r = 0; r < 3; ++r) if (on[r]) gl_lds16(b0 + goff[r], &tile[0][loff[r]]);
    #pragma unroll
    for (int r = 0; r < 3; ++r) if (on[r]) gl_lds16(b1 + goff[r], &tile[1][loff[r]]);
    asm volatile("s_waitcnt vmcnt(3) lgkmcnt(0)" ::: "memory"); // buf0 landed
  } else {
    asm volatile("s_waitcnt vmcnt(0) lgkmcnt(0)" ::: "memory");
  }
  __builtin_amdgcn_s_barrier();

  // Edge fixup flags: only these 2 thread-columns read the clamp-shifted cols;
  // the true values live in other slots of the same 8-float read.
  const bool fixl = (wbase == 0)   && (tx == 0);
  const bool fixr = (wbase == 128) && (tx == 15);

  float ring[5][5][4];  // [phase][channel:{I,J,II,JJ,IJ}][k]
  float acc = 0.0f;

  constexpr int T = CD + 4; // 10 steps; output d = d_lo + t - 4 for t>=4
  #pragma unroll
  for (int t = 0; t < T; ++t) {
    const int p = t % 5;                    // ring phase (compile-time: full unroll)
    const int s = d_lo - 2 + t;             // slice in current buffer tile[t%3]

    // ---- DMA slice d_lo+t (= s+2) into buf[(t+2)%3]; consumed at step t+2 ----
    const bool issue = ((t + 2) < T) && ((d_lo + t) < Dd);  // wave-uniform
    if (issue) {
      const float* base = gsrc + (long)(d_lo + t) * SD;
      float* dst = &tile[(t + 2) % 3][0];
      #pragma unroll
      for (int r = 0; r < 3; ++r) if (on[r]) gl_lds16(base + goff[r], dst + loff[r]);
    }

    // ---- H-window accumulate from current buffer ----
    float hsI[8], hsJ[8], hsII[8], hsJJ[8], hsIJ[8];
    #pragma unroll
    for (int c = 0; c < 8; ++c) {
      hsI[c] = 0.f; hsJ[c] = 0.f; hsII[c] = 0.f; hsJJ[c] = 0.f; hsIJ[c] = 0.f;
    }
    if (s >= 0 && s < Dd) {
      const float* bufc = &tile[t % 3][0];
      #pragma unroll
      for (int dh = 0; dh < 5; ++dh) {
        const int rrow = ty + dh;            // rows ty..ty+4 <-> hh = hbase+ty-2+dh
        const int hh = hbase + rrow - 2;
        if (hh >= 0 && hh < Hd) {            // skip clamped-duplicate halo rows
          const float* pa = bufc + rrow * TROW + 4 * tx;  // cols 4tx..4tx+7, 16B-aligned
          const float* pb = pa + 20 * TROW;  // J array
          float a[8], b[8];
          ((float4*)a)[0] = ((const float4*)pa)[0];
          ((float4*)a)[1] = ((const float4*)pa)[1];
          ((float4*)b)[0] = ((const float4*)pb)[0];
          ((float4*)b)[1] = ((const float4*)pb)[1];
          if (fixl) { a[2]=a[0]; a[3]=a[1]; a[0]=0.f; a[1]=0.f;
                      b[2]=b[0]; b[3]=b[1]; b[0]=0.f; b[1]=0.f; }
          if (fixr) { a[4]=a[6]; a[5]=a[7]; a[6]=0.f; a[7]=0.f;
                      b[4]=b[6]; b[5]=b[7]; b[6]=0.f; b[7]=0.f; }
          #pragma unroll
          for (int c = 0; c < 8; ++c) {
            const float x = a[c], y = b[c];  // cols w0-2..w0+5
            hsI[c]  += x;
            hsJ[c]  += y;
            hsII[c] = fmaf(x, x, hsII[c]);
            hsJJ[c] = fmaf(y, y, hsJJ[c]);
            hsIJ[c] = fmaf(x, y, hsIJ[c]);
          }
        }
      }
    }

    // ---- W-window sliding sums -> ring ----
    wslide(hsI,  ring[p][0]);
    wslide(hsJ,  ring[p][1]);
    wslide(hsII, ring[p][2]);
    wslide(hsJJ, ring[p][3]);
    wslide(hsIJ, ring[p][4]);

    // ---- D-window + cc ----
    const int d = d_lo + t - 4;
    if (t >= 4 && d < Dd) {
      #pragma unroll
      for (int k = 0; k < 4; ++k) {
        float SI = 0.f, SJ = 0.f, SII = 0.f, SJJ = 0.f, SIJ = 0.f;
        #pragma unroll
        for (int q = 0; q < 5; ++q) {
          SI  += ring[q][0][k];
          SJ  += ring[q][1][k];
          SII += ring[q][2][k];
          SJJ += ring[q][3][k];
          SIJ += ring[q][4][k];
        }
        const float cross = SIJ - SI * SJ * INV_V;
        const float vI    = SII - SI * SI * INV_V;
        const float vJ    = SJJ - SJ * SJ * INV_V;
        acc += cross * cross / (vI * vJ + EPSf);
      }
    }

    // ---- counted-wait barrier: drain step t-1's DMAs, keep this step's in flight ----
    if (issue) asm volatile("s_waitcnt vmcnt(3) lgkmcnt(0)" ::: "memory");
    else       asm volatile("s_waitcnt vmcnt(0) lgkmcnt(0)" ::: "memory");
    __builtin_amdgcn_s_barrier();
  }

  // ---- block reduction -> single atomic per block ----
  #pragma unroll
  for (int off = 32; off > 0; off >>= 1) acc += __shfl_xor(acc, off, 64);
  if ((tid & 63) == 0) red[tid >> 6] = acc;
  __syncthreads();
  if (tid == 0) {
    const float total = red[0] + red[1] + red[2] + red[3];
    atomicAdd(out, total * (-1.0f / 11796480.0f)); // -mean over 2*160*192*192
  }
}

extern "C" void kernel_launch(void* const* d_in, const int* in_sizes, int n_in,
                              void* d_out, int out_size, void* d_ws, size_t ws_size,
                              hipStream_t stream) {
  const float* I = (const float*)d_in[0];
  const float* J = (const float*)d_in[1];
  float* out = (float*)d_out;
  hipMemsetAsync(out, 0, sizeof(float), stream);
  dim3 grid(3, 12, 2 * NCHUNK); // W tiles * H tiles * (n x 27 d-chunks of 6)
  ncc_fused<<<grid, 256, 0, stream>>>(I, J, out);
}

// Round 4
// 169.058 us; speedup vs baseline: 1.2706x; 1.2706x over previous
//
#include <hip/hip_runtime.h>

// NCC loss, fused single pass. Layout [n][1][d][h][w], n=2, d=160, h=192, w=192, f32.
// R9: R8's distance-2 counted-wait pipeline with the prologue count bug fixed.
//   R8 NaN'd. Root cause (theory): the prologue issued 6 DMAs to TWO buffers
//   (buf0 x3 then buf1 x3) and waited vmcnt(3), assuming program order = issue
//   order. The two stage loops are independent intrinsics with disjoint LDS
//   destinations -> LLVM may interleave them; vmcnt(3) then drains a MIX and
//   leaves a buf0 segment in flight at the t=0 read -> stale-LDS garbage ->
//   inf/inf = NaN. Fix: prologue drains FULLY (vmcnt(0)). After that the
//   steady-state count is order-independent:
//     end of t=0: only S0's 3 in flight -> vmcnt(3) no-op (buf1 landed in prologue)
//     end of t>=1: exactly 6 in flight -> vmcnt(3) drains the older 3 = the
//                  buffer consumed at step t+1 (m135: oldest-first retirement)
//   All of a step's issues sit between two volatile "memory" asm waits, so any
//   in-step compiler reordering leaves the count invariant.
//   Pipeline protocol (guide T3/T4):
//     prologue: stage d_lo-2 -> buf0, d_lo-1 -> buf1; s_waitcnt vmcnt(0); s_barrier
//     step t:   issue DMA slice d_lo+t -> buf[(t+2)%3]  (3 gl_lds16 per wave)
//               compute from buf[t%3]
//               s_waitcnt vmcnt(3) lgkmcnt(0) (or vmcnt(0) on non-issuing steps,
//               block-uniform), s_barrier
//   RAW: ds_reads after the barrier can't hoist above the asm "memory" fence.
//   WAR: lgkmcnt(0) pre-barrier drains this wave's ds_reads before any wave's
//   next DMA can target the buffer just read (step t+1 writes buf[(t-1+3)%3]).
// R8 (kept): runtime ring index bc (0,1,2) keeps R6's register envelope; R7's
//   full-unroll variant exploded VGPR 92->204 and halved occupancy.
// R6 (kept): aligned layout col c <-> w = wbase-2+c; 2x aligned ds_read_b128 per
//   row/array; clamp-shift at the two W edges fixed by in-register permute (fixl/fixr).
// R5 (kept): all lanes always issue DMA with CLAMPED global addrs (m104/m108: LDS
//   dest is lane-linear from readfirstlane base; per-lane masking forbidden except
//   the r=2 tail lane<52 which keeps lane 0 active). H-OOB rows skipped in compute,
//   D-OOB slices skipped wave-uniformly, ring in registers, no occupancy clamp.

namespace {
constexpr int Wd = 192, Hd = 192, Dd = 160;
constexpr int SH = 192;              // h stride (floats)
constexpr int SD = 192 * 192;        // d stride
constexpr long SN = (long)SD * Dd;   // n stride
constexpr int CD = 6;                // d outputs per chunk; T = CD+4 = 10
constexpr int NCHUNK = 27;           // ceil(160/6)
constexpr int TROW = 72;             // LDS row stride (floats), unpadded (DMA lane map)
constexpr int TILEF = 2 * 20 * TROW; // floats per buffer (2880)
constexpr float INV_V = 1.0f / 125.0f;
constexpr float EPSf = 1e-5f;

__device__ __forceinline__ void wslide(const float h[8], float o[4]) {
  float s0 = h[0] + h[1] + h[2] + h[3] + h[4];
  float s1 = s0 - h[0] + h[5];
  float s2 = s1 - h[1] + h[6];
  float s3 = s2 - h[2] + h[7];
  o[0] = s0; o[1] = s1; o[2] = s2; o[3] = s3;
}

__device__ __forceinline__ void gl_lds16(const float* g, float* l) {
  __builtin_amdgcn_global_load_lds(
      (const __attribute__((address_space(1))) void*)g,
      (__attribute__((address_space(3))) void*)l, 16, 0, 0);
}
} // namespace

__global__ __launch_bounds__(256) void ncc_fused(const float* __restrict__ I,
                                                 const float* __restrict__ Jv,
                                                 float* __restrict__ out) {
  __shared__ float tile[3][TILEF];   // 34.56 KB triple buffer (prefetch distance 2)
  __shared__ float red[4];

  const int tid = threadIdx.x;
  const int tx = tid & 15;        // w-run index (4 outputs each)
  const int ty = tid >> 4;        // h row within 16-tall tile
  const int wbase = blockIdx.x * 64;
  const int hbase = blockIdx.y * 16;
  const int n  = blockIdx.z / NCHUNK;
  const int d_lo = (blockIdx.z % NCHUNK) * CD;

  const float* Ib = I  + (long)n * SN;
  const float* Jb = Jv + (long)n * SN;

  // ---- staging descriptors: 720 16B-segs; wave w owns segs [w*180,(w+1)*180) ----
  // seg = arr*360 + row*18 + c16 ; LDS byte-offset = seg*16 (consecutive per lane)
  // layout: LDS col c  <->  global w = wbase - 2 + c
  const int wave = tid >> 6, lane = tid & 63;
  const int arr = wave >> 1;                       // waves 0,1 -> I ; 2,3 -> J
  const float* gsrc = arr ? Jb : Ib;
  int goff[3]; int loff[3]; bool on[3];
  #pragma unroll
  for (int r = 0; r < 3; ++r) {
    const int seg = wave * 180 + r * 64 + lane;
    on[r] = (r < 2) || (lane < 52);                // 180 = 2*64 + 52 (lane 0 stays active)
    const int rem = seg - arr * 360;
    const int row = rem / 18, c16 = rem % 18;
    const int hh = hbase + row - 2;
    const int hc = min(max(hh, 0), Hd - 1);        // CLAMP, never mask
    const int gw = wbase - 2 + c16 * 4;
    const int gc = min(max(gw, 0), Wd - 4);
    goff[r] = hc * SH + gc;
    loff[r] = seg * 4;                             // float offset
  }

  // ---- prologue: stage slices d_lo-2 -> buf0, d_lo-1 -> buf1, drain FULLY ----
  // Both in-range iff d_lo > 0 (d_lo multiple of 6, max 156 -> 155 < Dd).
  if (d_lo > 0) {
    const float* b0 = gsrc + (long)(d_lo - 2) * SD;
    const float* b1 = gsrc + (long)(d_lo - 1) * SD;
    #pragma unroll
    for (int r = 0; r < 3; ++r) if (on[r]) gl_lds16(b0 + goff[r], &tile[0][loff[r]]);
    #pragma unroll
    for (int r = 0; r < 3; ++r) if (on[r]) gl_lds16(b1 + goff[r], &tile[1][loff[r]]);
  }
  asm volatile("s_waitcnt vmcnt(0) lgkmcnt(0)" ::: "memory"); // order-independent start
  __builtin_amdgcn_s_barrier();

  // Edge fixup flags: only these 2 thread-columns read the clamp-shifted cols;
  // the true values live in other slots of the same 8-float read.
  const bool fixl = (wbase == 0)   && (tx == 0);
  const bool fixr = (wbase == 128) && (tx == 15);

  float ring[5][5][4];  // [phase][channel:{I,J,II,JJ,IJ}][k]
  float acc = 0.0f;

  int bc = 0;  // runtime ring index: buf holding slice d_lo-2+t (t%3)
  constexpr int T = CD + 4; // 10 steps; output d = d_lo + t - 4 for t>=4
  for (int t0 = 0; t0 < T; t0 += 5) {
    #pragma unroll
    for (int p = 0; p < 5; ++p) {             // phase = t % 5 (compile-time)
      const int t = t0 + p;
      const int s = d_lo - 2 + t;             // slice in current buffer

      // ---- DMA slice d_lo+t (= s+2) into buf[(bc+2)%3]; consumed at step t+2 ----
      const bool issue = ((t + 2) < T) && ((d_lo + t) < Dd);  // block-uniform
      if (issue) {
        const float* base = gsrc + (long)(d_lo + t) * SD;
        int bw = bc - 1; if (bw < 0) bw += 3;          // (bc+2)%3
        float* dst = &tile[0][0] + bw * TILEF;
        #pragma unroll
        for (int r = 0; r < 3; ++r) if (on[r]) gl_lds16(base + goff[r], dst + loff[r]);
      }

      // ---- H-window accumulate from current buffer ----
      float hsI[8], hsJ[8], hsII[8], hsJJ[8], hsIJ[8];
      #pragma unroll
      for (int c = 0; c < 8; ++c) {
        hsI[c] = 0.f; hsJ[c] = 0.f; hsII[c] = 0.f; hsJJ[c] = 0.f; hsIJ[c] = 0.f;
      }
      if (s >= 0 && s < Dd) {
        const float* bufc = &tile[0][0] + bc * TILEF;
        #pragma unroll
        for (int dh = 0; dh < 5; ++dh) {
          const int rrow = ty + dh;            // rows ty..ty+4 <-> hh = hbase+ty-2+dh
          const int hh = hbase + rrow - 2;
          if (hh >= 0 && hh < Hd) {            // skip clamped-duplicate halo rows
            const float* pa = bufc + rrow * TROW + 4 * tx;  // cols 4tx..4tx+7, 16B-aligned
            const float* pb = pa + 20 * TROW;  // J array
            float a[8], b[8];
            ((float4*)a)[0] = ((const float4*)pa)[0];
            ((float4*)a)[1] = ((const float4*)pa)[1];
            ((float4*)b)[0] = ((const float4*)pb)[0];
            ((float4*)b)[1] = ((const float4*)pb)[1];
            if (fixl) { a[2]=a[0]; a[3]=a[1]; a[0]=0.f; a[1]=0.f;
                        b[2]=b[0]; b[3]=b[1]; b[0]=0.f; b[1]=0.f; }
            if (fixr) { a[4]=a[6]; a[5]=a[7]; a[6]=0.f; a[7]=0.f;
                        b[4]=b[6]; b[5]=b[7]; b[6]=0.f; b[7]=0.f; }
            #pragma unroll
            for (int c = 0; c < 8; ++c) {
              const float x = a[c], y = b[c];  // cols w0-2..w0+5
              hsI[c]  += x;
              hsJ[c]  += y;
              hsII[c] = fmaf(x, x, hsII[c]);
              hsJJ[c] = fmaf(y, y, hsJJ[c]);
              hsIJ[c] = fmaf(x, y, hsIJ[c]);
            }
          }
        }
      }

      // ---- W-window sliding sums -> ring ----
      wslide(hsI,  ring[p][0]);
      wslide(hsJ,  ring[p][1]);
      wslide(hsII, ring[p][2]);
      wslide(hsJJ, ring[p][3]);
      wslide(hsIJ, ring[p][4]);

      // ---- D-window + cc ----
      const int d = d_lo + t - 4;
      if (t >= 4 && d < Dd) {
        #pragma unroll
        for (int k = 0; k < 4; ++k) {
          float SI = 0.f, SJ = 0.f, SII = 0.f, SJJ = 0.f, SIJ = 0.f;
          #pragma unroll
          for (int q = 0; q < 5; ++q) {
            SI  += ring[q][0][k];
            SJ  += ring[q][1][k];
            SII += ring[q][2][k];
            SJJ += ring[q][3][k];
            SIJ += ring[q][4][k];
          }
          const float cross = SIJ - SI * SJ * INV_V;
          const float vI    = SII - SI * SI * INV_V;
          const float vJ    = SJJ - SJ * SJ * INV_V;
          acc += cross * cross / (vI * vJ + EPSf);
        }
      }

      // ---- counted-wait barrier: drain step t-1's DMAs, keep this step's in flight ----
      if (issue) asm volatile("s_waitcnt vmcnt(3) lgkmcnt(0)" ::: "memory");
      else       asm volatile("s_waitcnt vmcnt(0) lgkmcnt(0)" ::: "memory");
      __builtin_amdgcn_s_barrier();
      bc += 1; if (bc == 3) bc = 0;
    }
  }

  // ---- block reduction -> single atomic per block ----
  #pragma unroll
  for (int off = 32; off > 0; off >>= 1) acc += __shfl_xor(acc, off, 64);
  if ((tid & 63) == 0) red[tid >> 6] = acc;
  __syncthreads();
  if (tid == 0) {
    const float total = red[0] + red[1] + red[2] + red[3];
    atomicAdd(out, total * (-1.0f / 11796480.0f)); // -mean over 2*160*192*192
  }
}

extern "C" void kernel_launch(void* const* d_in, const int* in_sizes, int n_in,
                              void* d_out, int out_size, void* d_ws, size_t ws_size,
                              hipStream_t stream) {
  const float* I = (const float*)d_in[0];
  const float* J = (const float*)d_in[1];
  float* out = (float*)d_out;
  hipMemsetAsync(out, 0, sizeof(float), stream);
  dim3 grid(3, 12, 2 * NCHUNK); // W tiles * H tiles * (n x 27 d-chunks of 6)
  ncc_fused<<<grid, 256, 0, stream>>>(I, J, out);
}